// Round 4
// baseline (330.097 us; speedup 1.0000x reference)
//
#include <hip/hip_runtime.h>
#include <hip/hip_bf16.h>

typedef __bf16 bf16x8_t __attribute__((ext_vector_type(8)));
typedef __bf16 bf16x4_t __attribute__((ext_vector_type(4)));
typedef float  f32x4_t  __attribute__((ext_vector_type(4)));

#define MFMA_16x16x32_BF16(A, B, C) __builtin_amdgcn_mfma_f32_16x16x32_bf16((A), (B), (C), 0, 0, 0)

static constexpr int B_ = 16;
static constexpr int T_ = 2048;
static constexpr int C_ = 1024;
static constexpr int H_ = 128;
static constexpr long M_ = (long)B_ * T_;   // 32768 rows

// ---------------------------------------------------------------------------
// W transpose: WT[z][h][c] = bf16(W_z[c][h]).  Flat: WT[n][c], n = z*128+h.
// ---------------------------------------------------------------------------
__global__ __launch_bounds__(128) void wt_kernel(
    const float* __restrict__ Wq, const float* __restrict__ Wk,
    const float* __restrict__ Wv, __bf16* __restrict__ WT)
{
    const int z = blockIdx.y;
    const float* __restrict__ W = (z == 0) ? Wq : (z == 1) ? Wk : Wv;
    const int h  = threadIdx.x;
    const int c0 = blockIdx.x * 8;
    bf16x8_t v;
    #pragma unroll
    for (int j = 0; j < 8; ++j)
        v[j] = (__bf16)W[(c0 + j) * H_ + h];
    *(bf16x8_t*)&WT[((long)z * H_ + h) * C_ + c0] = v;
}

// ---------------------------------------------------------------------------
// Fused projection, v4: LDS-FREE, barrier-free direct-from-cache GEMM.
// Post-mortem model: v1-v3 were LDS-BW-bound (~224 KB LDS traffic /CU/k-step
// = ~5000 cyc vs 240 cyc MFMA). In this decomposition wave w's W rows and x
// rows are wave-PRIVATE -> the LDS round-trip was pure overhead. Delete it.
// Block = 256 thr / 4 waves, 64 rows; wave w: all 64 rows x 96 cols
// (n-frags w*6..w*6+5): 4 a-frags x 6 b-frags = 24 MFMA/k-step, b reused x4.
// b read directly from WT (768 KB, L2-resident); a read directly from x
// (fp32->bf16 cvt in-reg), x-regs double-buffered one k-step ahead.
// No __syncthreads, no LDS, no swizzle: 8 independent waves/CU; compiler
// pipelines freely. ~216 VGPR -> 2 waves/SIMD.
// ---------------------------------------------------------------------------
__global__ __launch_bounds__(256, 2) void proj_kernel(
    const float*  __restrict__ x,
    const __bf16* __restrict__ WT,
    __bf16* __restrict__ qo,
    __bf16* __restrict__ ko,
    __bf16* __restrict__ vo)
{
    const int tid  = threadIdx.x;
    const int w    = tid >> 6;
    const int lane = tid & 63;
    const int m16  = lane & 15;
    const int quad = lane >> 4;

    const long r0 = (long)blockIdx.x * 64;

    // per-lane base pointers (A: x rows r0+hh*16+m16; B: WT rows w*96+j*16+m16)
    const float*  __restrict__ xb = x  + (r0 + m16) * C_ + quad * 8;
    const __bf16* __restrict__ wb = WT + (long)(w * 96 + m16) * C_ + quad * 8;

    f32x4_t acc[4][6];
    #pragma unroll
    for (int hh = 0; hh < 4; ++hh)
        #pragma unroll
        for (int j = 0; j < 6; ++j) acc[hh][j] = f32x4_t{0, 0, 0, 0};

    f32x4_t xA[4][2], xB[4][2];

    // prologue: x k-step 0 into set A
    #pragma unroll
    for (int hh = 0; hh < 4; ++hh) {
        xA[hh][0] = *(const f32x4_t*)(xb + (long)hh * 16 * C_);
        xA[hh][1] = *(const f32x4_t*)(xb + (long)hh * 16 * C_ + 4);
    }

// One k-step: load 6 b-frags for step T, prefetch x for step T+1 into XN,
// cvt XC -> a-frags, 24 MFMAs. All loads at top so they overlap MFMAs.
#define PSTEP(T, XC, XN)                                                     \
    {                                                                        \
        const int t_  = (T);                                                 \
        const int k0_ = t_ * 32;                                             \
        bf16x8_t b_[6];                                                      \
        _Pragma("unroll")                                                    \
        for (int j = 0; j < 6; ++j)                                          \
            b_[j] = *(const bf16x8_t*)(wb + (long)j * 16 * C_ + k0_);        \
        if (t_ < 31) {                                                       \
            _Pragma("unroll")                                                \
            for (int hh = 0; hh < 4; ++hh) {                                 \
                XN[hh][0] = *(const f32x4_t*)(xb + (long)hh * 16 * C_ + k0_ + 32); \
                XN[hh][1] = *(const f32x4_t*)(xb + (long)hh * 16 * C_ + k0_ + 36); \
            }                                                                \
        }                                                                    \
        bf16x8_t a_[4];                                                      \
        _Pragma("unroll")                                                    \
        for (int hh = 0; hh < 4; ++hh)                                       \
            _Pragma("unroll")                                                \
            for (int jj = 0; jj < 4; ++jj) {                                 \
                a_[hh][jj]     = (__bf16)XC[hh][0][jj];                      \
                a_[hh][4 + jj] = (__bf16)XC[hh][1][jj];                      \
            }                                                                \
        _Pragma("unroll")                                                    \
        for (int j = 0; j < 6; ++j)                                          \
            _Pragma("unroll")                                                \
            for (int hh = 0; hh < 4; ++hh)                                   \
                acc[hh][j] = MFMA_16x16x32_BF16(a_[hh], b_[j], acc[hh][j]);  \
    }

    for (int tp = 0; tp < 16; ++tp) {
        PSTEP(2 * tp,     xA, xB);
        PSTEP(2 * tp + 1, xB, xA);
    }
#undef PSTEP

    // Epilogue. C/D: col = m16 (n), row = quad*4 + r (m).
    #pragma unroll
    for (int hh = 0; hh < 4; ++hh) {
        const long rbase = r0 + hh * 16 + quad * 4;
        #pragma unroll
        for (int j = 0; j < 6; ++j) {
            const int nt = w * 6 + j;
            const int z  = nt >> 3;
            const int h  = (nt & 7) * 16 + m16;
            if (z < 2) {
                __bf16* __restrict__ o = z ? ko : qo;
                #pragma unroll
                for (int r = 0; r < 4; ++r)
                    o[(rbase + r) * H_ + h] = (__bf16)acc[hh][j][r];
            } else {
                long bb = rbase >> 11, tt = rbase & 2047;  // rows stay in batch
                bf16x4_t pk;
                #pragma unroll
                for (int r = 0; r < 4; ++r) pk[r] = (__bf16)acc[hh][j][r];
                *(bf16x4_t*)&vo[bb * (H_ * (long)T_) + h * (long)T_ + tt] = pk;
            }
        }
    }
}

// ---------------------------------------------------------------------------
// Flash attention, causal, transposed-score, LDS-SHARED K/V tiles.
// (unchanged from the 275 µs baseline)
// ---------------------------------------------------------------------------
__global__ __launch_bounds__(256) void attn_kernel(
    const __bf16* __restrict__ q,   // [B][T][H]
    const __bf16* __restrict__ k,   // [B][T][H]
    const __bf16* __restrict__ vT,  // [B][H][T]
    float* __restrict__ out)        // [B][T][H] fp32
{
    __shared__ __bf16 KS[64 * 136];     // [krow][h], pad 8  (17.4 KB)
    __shared__ __bf16 VS[128 * 72];     // [h][t],    pad 8  (18.4 KB)
    __shared__ __bf16 PS[4][16 * 72];   // per-wave P [q][k], pad 8 (9.2 KB)

    const int L   = blockIdx.x;
    const int b   = L & 15;
    const int Lh  = L >> 4;                       // 0..31
    const int qb  = (Lh < 16) ? (31 - Lh) : (Lh - 16);   // heavy first, CU-paired

    const int tid  = threadIdx.x;
    const int w    = tid >> 6;
    const int lane = tid & 63;
    const int m16  = lane & 15;
    const int quad = lane >> 4;
    const int koff = quad * 8;

    const __bf16* __restrict__ qp = q  + (long)b * T_ * H_;
    const __bf16* __restrict__ kp = k  + (long)b * T_ * H_;
    const __bf16* __restrict__ vp = vT + (long)b * H_ * T_;

    const int q0w = qb * 64 + w * 16;             // wave's q-tile base
    const int qg  = q0w + m16;                    // this lane's q row

    // Q^T B-fragments (lane n=m16=q, k=h)
    bf16x8_t qfr[4];
    #pragma unroll
    for (int s = 0; s < 4; ++s)
        qfr[s] = *(const bf16x8_t*)&qp[(q0w + m16) * H_ + s * 32 + koff];

    f32x4_t acc[8];                               // O^T: row=h, col=q
    #pragma unroll
    for (int i = 0; i < 8; ++i) acc[i] = f32x4_t{0, 0, 0, 0};
    float mrun = -1e30f, lrun = 0.f;

    __bf16* Pb = &PS[w][0];
    const float SC = 0.08838834764831845f;        // 1/sqrt(128)
    const int kend = qb * 64 + 64;

    // staging coords
    const int krow = tid >> 4, kc16 = tid & 15;   // K: 16 thr/row (256B)
    const int vrow = tid >> 3, vc8  = tid & 7;    // V: 8 thr/row (128B)

    for (int tk0 = 0; tk0 < kend; tk0 += 64) {
        __syncthreads();                          // prev compute done
        #pragma unroll
        for (int ch = 0; ch < 4; ++ch) {
            int r = krow + ch * 16;
            *(bf16x8_t*)&KS[r * 136 + kc16 * 8] =
                *(const bf16x8_t*)&kp[(tk0 + r) * H_ + kc16 * 8];
        }
        #pragma unroll
        for (int ch = 0; ch < 4; ++ch) {
            int hh = vrow + ch * 32;
            *(bf16x8_t*)&VS[hh * 72 + vc8 * 8] =
                *(const bf16x8_t*)&vp[hh * (long)T_ + tk0 + vc8 * 8];
        }
        __syncthreads();                          // tiles ready

        // ---- S^T = K Q^T : 4 S-tiles of 16 k-rows ----
        f32x4_t st[4];
        #pragma unroll
        for (int kt = 0; kt < 4; ++kt) {
            f32x4_t s = f32x4_t{0, 0, 0, 0};
            #pragma unroll
            for (int sI = 0; sI < 4; ++sI) {
                bf16x8_t kf = *(const bf16x8_t*)&KS[(kt * 16 + m16) * 136 + sI * 32 + koff];
                s = MFMA_16x16x32_BF16(kf, qfr[sI], s);
            }
            st[kt] = s;
        }

        // ---- scale (+ causal mask only on boundary tiles, wave-uniform) ----
        float vv[4][4];
        if (tk0 + 63 <= q0w) {                    // fully unmasked
            #pragma unroll
            for (int kt = 0; kt < 4; ++kt)
                #pragma unroll
                for (int r = 0; r < 4; ++r)
                    vv[kt][r] = st[kt][r] * SC;
        } else {
            #pragma unroll
            for (int kt = 0; kt < 4; ++kt)
                #pragma unroll
                for (int r = 0; r < 4; ++r) {
                    int kg = tk0 + kt * 16 + quad * 4 + r;
                    vv[kt][r] = (kg <= qg) ? st[kt][r] * SC : -1e30f;
                }
        }

        float mloc = -1e30f;
        #pragma unroll
        for (int kt = 0; kt < 4; ++kt)
            #pragma unroll
            for (int r = 0; r < 4; ++r)
                mloc = fmaxf(mloc, vv[kt][r]);
        mloc = fmaxf(mloc, __shfl_xor(mloc, 16, 64));
        mloc = fmaxf(mloc, __shfl_xor(mloc, 32, 64));

        float mnew = fmaxf(mrun, mloc);
        float al   = __expf(mrun - mnew);
        float psum = 0.f;
        #pragma unroll
        for (int kt = 0; kt < 4; ++kt) {
            bf16x4_t pk;
            #pragma unroll
            for (int r = 0; r < 4; ++r) {
                float p = __expf(vv[kt][r] - mnew);
                psum += p;
                pk[r] = (__bf16)p;
            }
            *(bf16x4_t*)&Pb[m16 * 72 + kt * 16 + quad * 4] = pk;
        }
        psum += __shfl_xor(psum, 16, 64);
        psum += __shfl_xor(psum, 32, 64);
        mrun = mnew;
        lrun = lrun * al + psum;

        #pragma unroll
        for (int i = 0; i < 8; ++i)
            #pragma unroll
            for (int r = 0; r < 4; ++r)
                acc[i][r] *= al;

        // ---- O^T += V^T P^T : two K=32 halves over the 64-wide tile ----
        #pragma unroll
        for (int half = 0; half < 2; ++half) {
            bf16x8_t pa = *(const bf16x8_t*)&Pb[m16 * 72 + half * 32 + koff];
            #pragma unroll
            for (int i = 0; i < 8; ++i) {
                bf16x8_t vf = *(const bf16x8_t*)&VS[(i * 16 + m16) * 72 + half * 32 + koff];
                acc[i] = MFMA_16x16x32_BF16(vf, pa, acc[i]);
            }
        }
    }

    // ---- epilogue: O[q][h] = acc/lrun, f32x4 stores ----
    float* __restrict__ ob = out + (long)b * T_ * H_;
    const float inv = 1.f / lrun;
    #pragma unroll
    for (int i = 0; i < 8; ++i) {
        f32x4_t o;
        #pragma unroll
        for (int r = 0; r < 4; ++r) o[r] = acc[i][r] * inv;
        *(f32x4_t*)&ob[(q0w + m16) * H_ + i * 16 + quad * 4] = o;
    }
}

// ---------------------------------------------------------------------------
extern "C" void kernel_launch(void* const* d_in, const int* in_sizes, int n_in,
                              void* d_out, int out_size, void* d_ws, size_t ws_size,
                              hipStream_t stream)
{
    // setup_inputs order: x, Wk, Wq, Wv — all float32
    const float* x  = (const float*)d_in[0];
    const float* Wk = (const float*)d_in[1];
    const float* Wq = (const float*)d_in[2];
    const float* Wv = (const float*)d_in[3];

    // ws: q [M,H] bf16 | k [M,H] bf16 | vT [B][H][T] bf16 | WT [3][H][C] bf16
    __bf16* qws = (__bf16*)d_ws;
    __bf16* kws = qws + M_ * H_;
    __bf16* vws = kws + M_ * H_;
    __bf16* WT  = vws + (long)B_ * H_ * T_;
    float*  out = (float*)d_out;

    wt_kernel  <<<dim3(C_ / 8, 3), 128, 0, stream>>>(Wq, Wk, Wv, WT);
    proj_kernel<<<dim3((int)(M_ / 64)), 256, 0, stream>>>(x, WT, qws, kws, vws);
    attn_kernel<<<dim3(512), 256, 0, stream>>>(qws, kws, vws, out);
}

// Round 5
// 276.463 us; speedup vs baseline: 1.1940x; 1.1940x over previous
//
#include <hip/hip_runtime.h>
#include <hip/hip_bf16.h>

typedef __bf16 bf16x8_t __attribute__((ext_vector_type(8)));
typedef __bf16 bf16x4_t __attribute__((ext_vector_type(4)));
typedef float  f32x4_t  __attribute__((ext_vector_type(4)));

#define MFMA_16x16x32_BF16(A, B, C) __builtin_amdgcn_mfma_f32_16x16x32_bf16((A), (B), (C), 0, 0, 0)

static constexpr int B_ = 16;
static constexpr int T_ = 2048;
static constexpr int C_ = 1024;
static constexpr int H_ = 128;
static constexpr long M_ = (long)B_ * T_;   // 32768 rows

__device__ __forceinline__ void gload_lds16(const void* g, void* l)
{
    __builtin_amdgcn_global_load_lds(
        (const __attribute__((address_space(1))) void*)g,
        (__attribute__((address_space(3))) void*)l, 16, 0, 0);
}

// ---------------------------------------------------------------------------
// W transpose: WT[z][h][c] = bf16(W_z[c][h]).  Flat: WT[n][c], n = z*128+h.
// ---------------------------------------------------------------------------
__global__ __launch_bounds__(128) void wt_kernel(
    const float* __restrict__ Wq, const float* __restrict__ Wk,
    const float* __restrict__ Wv, __bf16* __restrict__ WT)
{
    const int z = blockIdx.y;
    const float* __restrict__ W = (z == 0) ? Wq : (z == 1) ? Wk : Wv;
    const int h  = threadIdx.x;
    const int c0 = blockIdx.x * 8;
    bf16x8_t v;
    #pragma unroll
    for (int j = 0; j < 8; ++j)
        v[j] = (__bf16)W[(c0 + j) * H_ + h];
    *(bf16x8_t*)&WT[((long)z * H_ + h) * C_ + c0] = v;
}

// ---------------------------------------------------------------------------
// Fused projection, v5: 128x384 block, 1 block/CU (grid 256), 8 waves (2m x
// 4n), wave = 64 rows x 96 cols -> 4 a-frags x 6 b-frags = 24 MFMA/k-step
// per 10 LDS reads (m97-class MFMA/byte).  v4 post-mortem: direct global
// frag reads are TA-transaction-bound (16 lines/load); LDS staging restores
// 1 KB coalesced loads.  v1-v3 post-mortem: drain-to-0 barriers + low
// MFMA/LDS-byte were the cost -> fix with T3/T4: THREE LDS buffers,
// prefetch distance 2, per-step vmcnt(5) BEFORE the barrier retires only
// step t+1's loads (cross-wave publication), loads never drained in-loop.
// All staging via global_load_lds (x as fp32, cvt at frag build).
// Swizzles (both-sides, v3-verified): W unit^=(row>>1)&3, x unit^=row&7.
// LDS 120 KB (3 x (16 KB x-f32 + 24 KB W)).
// ---------------------------------------------------------------------------
__global__ __launch_bounds__(512, 2) void proj_kernel(
    const float*  __restrict__ x,
    const __bf16* __restrict__ WT,
    __bf16* __restrict__ qo,
    __bf16* __restrict__ ko,
    __bf16* __restrict__ vo)
{
    __shared__ float  XS[3][128 * 32];   // fp32 x tiles, 16 KB each
    __shared__ __bf16 WS[3][384 * 32];   // bf16 W tiles, 24 KB each

    const int tid  = threadIdx.x;
    const int w    = tid >> 6;
    const int lane = tid & 63;
    const int m16  = lane & 15;
    const int quad = lane >> 4;
    const int wm   = w >> 2;             // row-half 0..1 (64 rows)
    const int wn   = w & 3;              // col-quarter 0..3 (6 n-tiles)

    const long r0 = (long)blockIdx.x * 128;

    // staging lane maps (pre-swizzled GLOBAL source, linear LDS dest)
    const int xl_row = lane >> 3;                     // row within 8-row chunk
    const int xl_u   = (lane & 7) ^ xl_row;           // f32 unit (4 floats)
    const int wl_row = lane >> 2;                     // row within 16-row chunk
    const int wl_u   = (lane & 3) ^ ((lane >> 3) & 3);// bf16 unit (8 elems)

    f32x4_t acc[4][6];
    #pragma unroll
    for (int hh = 0; hh < 4; ++hh)
        #pragma unroll
        for (int j = 0; j < 6; ++j) acc[hh][j] = f32x4_t{0, 0, 0, 0};

// Issue one k-step's staging: 2 x-chunks (8 rows/wave) + 3 W-chunks
// (16 rows/wave) = 5 gload_lds16 per thread, 40 KB per block.
#define ISSUE(T, BUF)                                                        \
    {                                                                        \
        const int k0_ = (T) * 32;                                            \
        _Pragma("unroll")                                                    \
        for (int ch = 0; ch < 2; ++ch) {                                     \
            const int rb = w * 8 + ch * 64;                                  \
            gload_lds16(&x[(r0 + rb + xl_row) * C_ + k0_ + xl_u * 4],        \
                        &XS[BUF][rb * 32]);                                  \
        }                                                                    \
        _Pragma("unroll")                                                    \
        for (int ch = 0; ch < 3; ++ch) {                                     \
            const int rb = w * 48 + ch * 16;                                 \
            gload_lds16(&WT[(long)(rb + wl_row) * C_ + k0_ + wl_u * 8],      \
                        &WS[BUF][rb * 32]);                                  \
        }                                                                    \
    }

    // ---- prologue: buffers 0 and 1 in flight; wait only for buffer 0 ----
    ISSUE(0, 0);
    ISSUE(1, 1);
    asm volatile("s_waitcnt vmcnt(5)" ::: "memory");
    __builtin_amdgcn_sched_barrier(0);
    __builtin_amdgcn_s_barrier();
    __builtin_amdgcn_sched_barrier(0);

    const int asw = m16 & 7;                           // x unit swizzle
    const int qsw = (quad ^ ((m16 >> 1) & 3)) << 3;    // W bf16-elem offset

    for (int t = 0; t < 32; ++t) {
        const int cur = t % 3;
        if (t + 2 < 32) ISSUE(t + 2, (t + 2) % 3);
        __builtin_amdgcn_sched_barrier(0);

        // a-frags: fp32 -> bf16, swizzled read
        bf16x8_t a[4];
        #pragma unroll
        for (int hh = 0; hh < 4; ++hh) {
            const int row = wm * 64 + hh * 16 + m16;
            f32x4_t lo = *(const f32x4_t*)&XS[cur][row * 32 + (((quad * 2 + 0) ^ asw) << 2)];
            f32x4_t hi = *(const f32x4_t*)&XS[cur][row * 32 + (((quad * 2 + 1) ^ asw) << 2)];
            #pragma unroll
            for (int jj = 0; jj < 4; ++jj) {
                a[hh][jj]     = (__bf16)lo[jj];
                a[hh][4 + jj] = (__bf16)hi[jj];
            }
        }
        // b-frags + 24 MFMAs (b reused x4)
        #pragma unroll
        for (int j = 0; j < 6; ++j) {
            const int row = wn * 96 + j * 16 + m16;
            bf16x8_t b = *(const bf16x8_t*)&WS[cur][row * 32 + qsw];
            #pragma unroll
            for (int hh = 0; hh < 4; ++hh)
                acc[hh][j] = MFMA_16x16x32_BF16(a[hh], b, acc[hh][j]);
        }

        __builtin_amdgcn_sched_barrier(0);
        if (t + 2 < 32) asm volatile("s_waitcnt vmcnt(5)" ::: "memory");
        else            asm volatile("s_waitcnt vmcnt(0)" ::: "memory");
        asm volatile("s_waitcnt lgkmcnt(0)" ::: "memory");
        __builtin_amdgcn_s_barrier();          // publish buf[t+1]; reads done
        __builtin_amdgcn_sched_barrier(0);
    }
#undef ISSUE

    // Epilogue. C/D: col = m16 (n), row = quad*4 + r (m).
    #pragma unroll
    for (int hh = 0; hh < 4; ++hh) {
        const long rbase = r0 + wm * 64 + hh * 16 + quad * 4;
        #pragma unroll
        for (int j = 0; j < 6; ++j) {
            const int nt = wn * 6 + j;
            const int z  = nt >> 3;
            const int h  = (nt & 7) * 16 + m16;
            if (z < 2) {
                __bf16* __restrict__ o = z ? ko : qo;
                #pragma unroll
                for (int r = 0; r < 4; ++r)
                    o[(rbase + r) * H_ + h] = (__bf16)acc[hh][j][r];
            } else {
                long bb = rbase >> 11, tt = rbase & 2047;  // rows stay in batch
                bf16x4_t pk;
                #pragma unroll
                for (int r = 0; r < 4; ++r) pk[r] = (__bf16)acc[hh][j][r];
                *(bf16x4_t*)&vo[bb * (H_ * (long)T_) + h * (long)T_ + tt] = pk;
            }
        }
    }
}

// ---------------------------------------------------------------------------
// Flash attention, causal, transposed-score, LDS-SHARED K/V tiles.
// (unchanged from the 275 µs baseline)
// ---------------------------------------------------------------------------
__global__ __launch_bounds__(256) void attn_kernel(
    const __bf16* __restrict__ q,   // [B][T][H]
    const __bf16* __restrict__ k,   // [B][T][H]
    const __bf16* __restrict__ vT,  // [B][H][T]
    float* __restrict__ out)        // [B][T][H] fp32
{
    __shared__ __bf16 KS[64 * 136];     // [krow][h], pad 8  (17.4 KB)
    __shared__ __bf16 VS[128 * 72];     // [h][t],    pad 8  (18.4 KB)
    __shared__ __bf16 PS[4][16 * 72];   // per-wave P [q][k], pad 8 (9.2 KB)

    const int L   = blockIdx.x;
    const int b   = L & 15;
    const int Lh  = L >> 4;                       // 0..31
    const int qb  = (Lh < 16) ? (31 - Lh) : (Lh - 16);   // heavy first, CU-paired

    const int tid  = threadIdx.x;
    const int w    = tid >> 6;
    const int lane = tid & 63;
    const int m16  = lane & 15;
    const int quad = lane >> 4;
    const int koff = quad * 8;

    const __bf16* __restrict__ qp = q  + (long)b * T_ * H_;
    const __bf16* __restrict__ kp = k  + (long)b * T_ * H_;
    const __bf16* __restrict__ vp = vT + (long)b * H_ * T_;

    const int q0w = qb * 64 + w * 16;             // wave's q-tile base
    const int qg  = q0w + m16;                    // this lane's q row

    // Q^T B-fragments (lane n=m16=q, k=h)
    bf16x8_t qfr[4];
    #pragma unroll
    for (int s = 0; s < 4; ++s)
        qfr[s] = *(const bf16x8_t*)&qp[(q0w + m16) * H_ + s * 32 + koff];

    f32x4_t acc[8];                               // O^T: row=h, col=q
    #pragma unroll
    for (int i = 0; i < 8; ++i) acc[i] = f32x4_t{0, 0, 0, 0};
    float mrun = -1e30f, lrun = 0.f;

    __bf16* Pb = &PS[w][0];
    const float SC = 0.08838834764831845f;        // 1/sqrt(128)
    const int kend = qb * 64 + 64;

    // staging coords
    const int krow = tid >> 4, kc16 = tid & 15;   // K: 16 thr/row (256B)
    const int vrow = tid >> 3, vc8  = tid & 7;    // V: 8 thr/row (128B)

    for (int tk0 = 0; tk0 < kend; tk0 += 64) {
        __syncthreads();                          // prev compute done
        #pragma unroll
        for (int ch = 0; ch < 4; ++ch) {
            int r = krow + ch * 16;
            *(bf16x8_t*)&KS[r * 136 + kc16 * 8] =
                *(const bf16x8_t*)&kp[(tk0 + r) * H_ + kc16 * 8];
        }
        #pragma unroll
        for (int ch = 0; ch < 4; ++ch) {
            int hh = vrow + ch * 32;
            *(bf16x8_t*)&VS[hh * 72 + vc8 * 8] =
                *(const bf16x8_t*)&vp[hh * (long)T_ + tk0 + vc8 * 8];
        }
        __syncthreads();                          // tiles ready

        // ---- S^T = K Q^T : 4 S-tiles of 16 k-rows ----
        f32x4_t st[4];
        #pragma unroll
        for (int kt = 0; kt < 4; ++kt) {
            f32x4_t s = f32x4_t{0, 0, 0, 0};
            #pragma unroll
            for (int sI = 0; sI < 4; ++sI) {
                bf16x8_t kf = *(const bf16x8_t*)&KS[(kt * 16 + m16) * 136 + sI * 32 + koff];
                s = MFMA_16x16x32_BF16(kf, qfr[sI], s);
            }
            st[kt] = s;
        }

        // ---- scale (+ causal mask only on boundary tiles, wave-uniform) ----
        float vv[4][4];
        if (tk0 + 63 <= q0w) {                    // fully unmasked
            #pragma unroll
            for (int kt = 0; kt < 4; ++kt)
                #pragma unroll
                for (int r = 0; r < 4; ++r)
                    vv[kt][r] = st[kt][r] * SC;
        } else {
            #pragma unroll
            for (int kt = 0; kt < 4; ++kt)
                #pragma unroll
                for (int r = 0; r < 4; ++r) {
                    int kg = tk0 + kt * 16 + quad * 4 + r;
                    vv[kt][r] = (kg <= qg) ? st[kt][r] * SC : -1e30f;
                }
        }

        float mloc = -1e30f;
        #pragma unroll
        for (int kt = 0; kt < 4; ++kt)
            #pragma unroll
            for (int r = 0; r < 4; ++r)
                mloc = fmaxf(mloc, vv[kt][r]);
        mloc = fmaxf(mloc, __shfl_xor(mloc, 16, 64));
        mloc = fmaxf(mloc, __shfl_xor(mloc, 32, 64));

        float mnew = fmaxf(mrun, mloc);
        float al   = __expf(mrun - mnew);
        float psum = 0.f;
        #pragma unroll
        for (int kt = 0; kt < 4; ++kt) {
            bf16x4_t pk;
            #pragma unroll
            for (int r = 0; r < 4; ++r) {
                float p = __expf(vv[kt][r] - mnew);
                psum += p;
                pk[r] = (__bf16)p;
            }
            *(bf16x4_t*)&Pb[m16 * 72 + kt * 16 + quad * 4] = pk;
        }
        psum += __shfl_xor(psum, 16, 64);
        psum += __shfl_xor(psum, 32, 64);
        mrun = mnew;
        lrun = lrun * al + psum;

        #pragma unroll
        for (int i = 0; i < 8; ++i)
            #pragma unroll
            for (int r = 0; r < 4; ++r)
                acc[i][r] *= al;

        // ---- O^T += V^T P^T : two K=32 halves over the 64-wide tile ----
        #pragma unroll
        for (int half = 0; half < 2; ++half) {
            bf16x8_t pa = *(const bf16x8_t*)&Pb[m16 * 72 + half * 32 + koff];
            #pragma unroll
            for (int i = 0; i < 8; ++i) {
                bf16x8_t vf = *(const bf16x8_t*)&VS[(i * 16 + m16) * 72 + half * 32 + koff];
                acc[i] = MFMA_16x16x32_BF16(vf, pa, acc[i]);
            }
        }
    }

    // ---- epilogue: O[q][h] = acc/lrun, f32x4 stores ----
    float* __restrict__ ob = out + (long)b * T_ * H_;
    const float inv = 1.f / lrun;
    #pragma unroll
    for (int i = 0; i < 8; ++i) {
        f32x4_t o;
        #pragma unroll
        for (int r = 0; r < 4; ++r) o[r] = acc[i][r] * inv;
        *(f32x4_t*)&ob[(q0w + m16) * H_ + i * 16 + quad * 4] = o;
    }
}

// ---------------------------------------------------------------------------
extern "C" void kernel_launch(void* const* d_in, const int* in_sizes, int n_in,
                              void* d_out, int out_size, void* d_ws, size_t ws_size,
                              hipStream_t stream)
{
    // setup_inputs order: x, Wk, Wq, Wv — all float32
    const float* x  = (const float*)d_in[0];
    const float* Wk = (const float*)d_in[1];
    const float* Wq = (const float*)d_in[2];
    const float* Wv = (const float*)d_in[3];

    // ws: q [M,H] bf16 | k [M,H] bf16 | vT [B][H][T] bf16 | WT [3][H][C] bf16
    __bf16* qws = (__bf16*)d_ws;
    __bf16* kws = qws + M_ * H_;
    __bf16* vws = kws + M_ * H_;
    __bf16* WT  = vws + (long)B_ * H_ * T_;
    float*  out = (float*)d_out;

    wt_kernel  <<<dim3(C_ / 8, 3), 128, 0, stream>>>(Wq, Wk, Wv, WT);
    proj_kernel<<<dim3((int)(M_ / 128)), 512, 0, stream>>>(x, WT, qws, kws, vws);
    attn_kernel<<<dim3(512), 256, 0, stream>>>(qws, kws, vws, out);
}